// Round 6
// baseline (2506.636 us; speedup 1.0000x reference)
//
#include <hip/hip_runtime.h>

#define N_NODES 20000
#define D 128
#define E_EDGES 320000
#define G 100
#define L_LAYERS 6
#define IN_DIM 5
#define ZROW (IN_DIM + D)
#define CUTOFF_V 10.0f
#define LOG2F_ 0.69314718055994530942f

typedef __attribute__((ext_vector_type(8))) short bf16x8;
typedef __attribute__((ext_vector_type(4))) float f32x4;
typedef unsigned short ushort_t;
typedef unsigned int uint_t;

__device__ __forceinline__ float sspf(float x) {
    return fmaxf(x, 0.0f) + __logf(1.0f + __expf(-fabsf(x))) - LOG2F_;
}

__device__ __forceinline__ ushort_t f2bf(float f) {
    union { float f; uint_t u; } x; x.f = f;
    uint_t r = ((x.u >> 16) & 1u) + 0x7fffu;
    return (ushort_t)((x.u + r) >> 16);
}

__device__ __forceinline__ uint_t pack2(float a, float b) {
    return (uint_t)f2bf(a) | ((uint_t)f2bf(b) << 16);
}

__device__ __forceinline__ float bflo(uint_t u) { return __uint_as_float(u << 16); }
__device__ __forceinline__ float bfhi(uint_t u) { return __uint_as_float(u & 0xffff0000u); }

__device__ __forceinline__ f32x4 mfma_bf16(bf16x8 a, bf16x8 b, f32x4 c) {
    return __builtin_amdgcn_mfma_f32_16x16x32_bf16(a, b, c, 0, 0, 0);
}

// ---------------------------------------------------------------------------
__global__ void embed_kernel(const float* __restrict__ z,
                             const float* __restrict__ ew,
                             const float* __restrict__ eb,
                             float* __restrict__ h) {
    int n = blockIdx.x;
    int d = threadIdx.x;
    const float* zr = z + (size_t)n * ZROW;
    float acc = eb[d] + zr[IN_DIM + d];
#pragma unroll
    for (int k = 0; k < IN_DIM; ++k) acc += zr[k] * ew[d * IN_DIM + k];
    h[(size_t)n * D + d] = acc;
}

// ---------------------------------------------------------------------------
__global__ void convw1_kernel(const float* __restrict__ w1, ushort_t* __restrict__ out) {
    int idx = blockIdx.x * 256 + threadIdx.x;
    int k = idx & 127;
    int nl = idx >> 7;
    out[idx] = (k < G) ? f2bf(w1[(size_t)nl * G + k]) : (ushort_t)0;
}

__global__ void castbf_kernel(const float* __restrict__ src, ushort_t* __restrict__ dst) {
    int i = blockIdx.x * 256 + threadIdx.x;
    dst[i] = f2bf(src[i]);
}

// ---------------------------------------------------------------------------
// CSR build (edge graph constant across layers)
__global__ void hist_kernel(const int* __restrict__ ei, int* __restrict__ deg) {
    int e = blockIdx.x * 256 + threadIdx.x;
    atomicAdd(&deg[ei[E_EDGES + e]], 1);
}

__global__ __launch_bounds__(1024) void scan_kernel(const int* __restrict__ deg,
                                                    int* __restrict__ row_start,
                                                    int* __restrict__ cursor) {
    __shared__ int wsum[16];
    int t = threadIdx.x;
    const int CH = (N_NODES + 1023) / 1024;
    int base = t * CH;
    int s = 0;
    for (int i = 0; i < CH; ++i) {
        int idx = base + i;
        if (idx < N_NODES) s += deg[idx];
    }
    int lane = t & 63, wid = t >> 6;
    int v = s;
    for (int o = 1; o < 64; o <<= 1) {
        int u = __shfl_up(v, o, 64);
        if (lane >= o) v += u;
    }
    if (lane == 63) wsum[wid] = v;
    __syncthreads();
    if (t == 0) {
        int acc = 0;
        for (int i = 0; i < 16; ++i) { int tmp = wsum[i]; wsum[i] = acc; acc += tmp; }
    }
    __syncthreads();
    int run = v - s + wsum[wid];
    for (int i = 0; i < CH; ++i) {
        int idx = base + i;
        if (idx < N_NODES) {
            row_start[idx] = run;
            cursor[idx] = run;
            run += deg[idx];
        }
    }
    if (t == 0) row_start[N_NODES] = E_EDGES;
}

__global__ void scatter_perm_kernel(const int* __restrict__ ei, int* __restrict__ cursor,
                                    int* __restrict__ perm, int* __restrict__ src_p,
                                    int* __restrict__ dst_p) {
    int e = blockIdx.x * 256 + threadIdx.x;
    int d = ei[E_EDGES + e];
    int p = atomicAdd(&cursor[d], 1);
    perm[p] = e;
    src_p[p] = ei[e];
    dst_p[p] = d;
}

// ---------------------------------------------------------------------------
__global__ void attr_prep_kernel(const float* __restrict__ ea,
                                 const int* __restrict__ perm,
                                 ushort_t* __restrict__ attr_bf) {
    int t = threadIdx.x;
    int half = t >> 5;
    int ch = t & 31;
    int r = blockIdx.x * 8 + half;
    int pe = perm[r];
    float4 v = make_float4(0.f, 0.f, 0.f, 0.f);
    if (ch < 25) v = *(const float4*)(ea + (size_t)pe * G + ch * 4);
    uint2 p; p.x = pack2(v.x, v.y); p.y = pack2(v.z, v.w);
    *(uint2*)(attr_bf + (size_t)r * 128 + ch * 4) = p;
}

__global__ void cmask_kernel(const float* __restrict__ el, const int* __restrict__ perm,
                             float* __restrict__ c_mask) {
    int e = blockIdx.x * 256 + threadIdx.x;
    c_mask[e] = (el[perm[e]] <= CUTOFF_V) ? 1.0f : 0.0f;
}

// ---------------------------------------------------------------------------
// Fused edge MLP + segment sum, NODE-RANGE OWNED (zero atomics, zero memset).
// Wave owns nodes [w0, w0+8): its dst-sorted edge run is contiguous in CSR.
// Chunks of 32 edges (2 x 16-edge MFMA groups sharing weight A-frags).
// Per-lane running sums (cols j, j+64) carry across chunks; each m_i row is
// plain-stored exactly once; skipped (degree-0) nodes get explicit zeros.
__global__ __launch_bounds__(128, 2) void edge_fused_kernel(
    const ushort_t* __restrict__ attr_bf, const float* __restrict__ c_mask,
    const int* __restrict__ src_p, const int* __restrict__ dst_p,
    const int* __restrict__ row_start, const ushort_t* __restrict__ xf_bf,
    const ushort_t* __restrict__ w1b, const float* __restrict__ b1,
    const ushort_t* __restrict__ w2b, const float* __restrict__ b2,
    float* __restrict__ m_i) {
    __shared__ __align__(16) ushort_t sU[2][32 * 136];
    int t = threadIdx.x, lane = t & 63, wid = t >> 6;
    int c = lane & 15, quad = lane >> 4;
    int j = lane;
    int w0 = (blockIdx.x * 2 + wid) * 8;
    int beg = row_start[w0], end = row_start[w0 + 8];

    ushort_t* sUW = &sU[wid][0];
    float* sPf = (float*)sUW;

    float s0 = 0.f, s1 = 0.f;
    int nextn = w0, dprev = -1;
    if (beg < end) dprev = dst_p[beg];

    int nch = (end - beg + 31) >> 5;

    int dstv = 0, srcv = 0;
    float cvv = 0.f;
    bf16x8 p0[4], p1[4];

    auto fetch = [&](int ci) {
        int ebase = beg + ci * 32;
        if (lane < 32) {
            int myE = min(ebase + lane, end - 1);
            dstv = dst_p[myE];
            srcv = src_p[myE];
            cvv = (ebase + lane < end) ? c_mask[myE] : 0.f;
        }
        int eg0 = min(ebase + c, end - 1);
        int eg1 = min(ebase + 16 + c, end - 1);
#pragma unroll
        for (int ks = 0; ks < 4; ++ks) {
            p0[ks] = *(const bf16x8*)(attr_bf + (size_t)eg0 * 128 + ks * 32 + quad * 8);
            p1[ks] = *(const bf16x8*)(attr_bf + (size_t)eg1 * 128 + ks * 32 + quad * 8);
        }
    };
    if (nch > 0) fetch(0);

#pragma unroll 1
    for (int ci = 0; ci < nch; ++ci) {
        int dcur = dstv, scur = srcv;
        float ccur = cvv;
        bf16x8 a0[4], a1[4];
#pragma unroll
        for (int ks = 0; ks < 4; ++ks) { a0[ks] = p0[ks]; a1[ks] = p1[ks]; }

        // xf gather for both groups (issued early; consumed after GEMM2)
        int sn0 = __shfl(scur, c);
        int sn1 = __shfl(scur, 16 + c);
        float cv0 = __shfl(ccur, c);
        float cv1 = __shfl(ccur, 16 + c);
        uint2 xr0[8], xr1[8];
#pragma unroll
        for (int ct = 0; ct < 8; ++ct) {
            xr0[ct] = *(const uint2*)(xf_bf + (size_t)sn0 * 128 + ct * 16 + quad * 4);
            xr1[ct] = *(const uint2*)(xf_bf + (size_t)sn1 * 128 + ct * 16 + quad * 4);
        }

        if (ci + 1 < nch) fetch(ci + 1);

        // GEMM1: shared weight A-frag, two edge groups
        f32x4 A0[8], A1[8];
#pragma unroll
        for (int i = 0; i < 8; ++i) { A0[i] = (f32x4){0,0,0,0}; A1[i] = (f32x4){0,0,0,0}; }
#pragma unroll
        for (int ks = 0; ks < 4; ++ks)
#pragma unroll
            for (int ct = 0; ct < 8; ++ct) {
                bf16x8 a = *(const bf16x8*)(w1b + (size_t)(ct * 16 + c) * 128 + ks * 32 + quad * 8);
                A0[ct] = mfma_bf16(a, a0[ks], A0[ct]);
                A1[ct] = mfma_bf16(a, a1[ks], A1[ct]);
            }
        // epi1: u = ssp(acc + b1) -> LDS rows [c] (g0) and [16+c] (g1)
#pragma unroll
        for (int ct = 0; ct < 8; ++ct) {
            int col = ct * 16 + quad * 4;
            float4 bv = *(const float4*)(b1 + col);
            uint2 pA, pB;
            pA.x = pack2(sspf(A0[ct][0] + bv.x), sspf(A0[ct][1] + bv.y));
            pA.y = pack2(sspf(A0[ct][2] + bv.z), sspf(A0[ct][3] + bv.w));
            pB.x = pack2(sspf(A1[ct][0] + bv.x), sspf(A1[ct][1] + bv.y));
            pB.y = pack2(sspf(A1[ct][2] + bv.z), sspf(A1[ct][3] + bv.w));
            *(uint2*)(sUW + (size_t)c * 136 + col) = pA;
            *(uint2*)(sUW + (size_t)(16 + c) * 136 + col) = pB;
        }
        // u fragments into registers (all LDS reads done before product overwrite)
        bf16x8 u0[4], u1[4];
#pragma unroll
        for (int ks = 0; ks < 4; ++ks) {
            u0[ks] = *(const bf16x8*)(sUW + (size_t)c * 136 + ks * 32 + quad * 8);
            u1[ks] = *(const bf16x8*)(sUW + (size_t)(16 + c) * 136 + ks * 32 + quad * 8);
        }
        // GEMM2
#pragma unroll
        for (int i = 0; i < 8; ++i) { A0[i] = (f32x4){0,0,0,0}; A1[i] = (f32x4){0,0,0,0}; }
#pragma unroll
        for (int ks = 0; ks < 4; ++ks)
#pragma unroll
            for (int ct = 0; ct < 8; ++ct) {
                bf16x8 a = *(const bf16x8*)(w2b + (size_t)(ct * 16 + c) * 128 + ks * 32 + quad * 8);
                A0[ct] = mfma_bf16(a, u0[ks], A0[ct]);
                A1[ct] = mfma_bf16(a, u1[ks], A1[ct]);
            }

        // ---- group 0: products -> LDS (fp32), then carry-reduce
#pragma unroll
        for (int ct = 0; ct < 8; ++ct) {
            int col = ct * 16 + quad * 4;
            float4 bv = *(const float4*)(b2 + col);
            float4 pr;
            pr.x = (A0[ct][0] + bv.x) * cv0 * bflo(xr0[ct].x);
            pr.y = (A0[ct][1] + bv.y) * cv0 * bfhi(xr0[ct].x);
            pr.z = (A0[ct][2] + bv.z) * cv0 * bflo(xr0[ct].y);
            pr.w = (A0[ct][3] + bv.w) * cv0 * bfhi(xr0[ct].y);
            *(float4*)(sPf + (size_t)c * 136 + col) = pr;
        }
#pragma unroll 1
        for (int e = 0; e < 16; ++e) {
            int d = __shfl(dcur, e);
            if (d != dprev) {
                for (int n = nextn; n < d; ++n) {
                    m_i[(size_t)n * 128 + j]      = (n == dprev) ? s0 : 0.f;
                    m_i[(size_t)n * 128 + 64 + j] = (n == dprev) ? s1 : 0.f;
                }
                nextn = d; dprev = d; s0 = 0.f; s1 = 0.f;
            }
            s0 += sPf[e * 136 + j];
            s1 += sPf[e * 136 + 64 + j];
        }
        // ---- group 1
#pragma unroll
        for (int ct = 0; ct < 8; ++ct) {
            int col = ct * 16 + quad * 4;
            float4 bv = *(const float4*)(b2 + col);
            float4 pr;
            pr.x = (A1[ct][0] + bv.x) * cv1 * bflo(xr1[ct].x);
            pr.y = (A1[ct][1] + bv.y) * cv1 * bfhi(xr1[ct].x);
            pr.z = (A1[ct][2] + bv.z) * cv1 * bflo(xr1[ct].y);
            pr.w = (A1[ct][3] + bv.w) * cv1 * bfhi(xr1[ct].y);
            *(float4*)(sPf + (size_t)c * 136 + col) = pr;
        }
#pragma unroll 1
        for (int e = 0; e < 16; ++e) {
            int d = __shfl(dcur, 16 + e);
            if (d != dprev) {
                for (int n = nextn; n < d; ++n) {
                    m_i[(size_t)n * 128 + j]      = (n == dprev) ? s0 : 0.f;
                    m_i[(size_t)n * 128 + 64 + j] = (n == dprev) ? s1 : 0.f;
                }
                nextn = d; dprev = d; s0 = 0.f; s1 = 0.f;
            }
            s0 += sPf[e * 136 + j];
            s1 += sPf[e * 136 + 64 + j];
        }
    }
    // final flush: remaining nodes of the owned range (incl. degree-0 zeros)
    for (int n = nextn; n < w0 + 8; ++n) {
        m_i[(size_t)n * 128 + j]      = (n == dprev) ? s0 : 0.f;
        m_i[(size_t)n * 128 + 64 + j] = (n == dprev) ? s1 : 0.f;
    }
}

// ---------------------------------------------------------------------------
// Node GEMM on MFMA (round-3 proven): 128 nodes/block.
template <bool HASB, bool SSP, bool RES, bool BF16OUT, bool TWOK>
__global__ __launch_bounds__(256) void node_mfma_kernel(
    const float* __restrict__ in0, const float* __restrict__ in1,
    const ushort_t* __restrict__ Wb, const float* __restrict__ bias,
    const float* __restrict__ resid, void* __restrict__ outp) {
    __shared__ __align__(16) ushort_t sT[128][136];
    const int WS = TWOK ? 256 : 128;
    int t = threadIdx.x, lane = t & 63, wid = t >> 6;
    int c = lane & 15, quad = lane >> 4;
    int n0 = blockIdx.x * 128, rbase = wid * 32;

    f32x4 acc[2][8];
#pragma unroll
    for (int st = 0; st < 2; ++st)
#pragma unroll
        for (int ct = 0; ct < 8; ++ct) acc[st][ct] = (f32x4){0.f, 0.f, 0.f, 0.f};

    const float* src = in0;
#pragma unroll 1
    for (int ph = 0; ph < (TWOK ? 2 : 1); ++ph) {
#pragma unroll
        for (int i = 0; i < 16; ++i) {
            int idx = i * 64 + lane;
            int r = idx >> 5, ch = idx & 31;
            int gr = n0 + rbase + r;
            float4 v = make_float4(0.f, 0.f, 0.f, 0.f);
            if (gr < N_NODES) v = *(const float4*)(src + (size_t)gr * 128 + ch * 4);
            uint2 p; p.x = pack2(v.x, v.y); p.y = pack2(v.z, v.w);
            *(uint2*)(&sT[rbase + r][ch * 4]) = p;
        }
        int kb = ph * 128;
#pragma unroll
        for (int ks = 0; ks < 4; ++ks) {
            int koff = ks * 32 + quad * 8;
            bf16x8 b0 = *(const bf16x8*)(&sT[rbase + c][koff]);
            bf16x8 b1v = *(const bf16x8*)(&sT[rbase + 16 + c][koff]);
#pragma unroll
            for (int ct = 0; ct < 8; ++ct) {
                bf16x8 a = *(const bf16x8*)(Wb + (size_t)(ct * 16 + c) * WS + kb + koff);
                acc[0][ct] = mfma_bf16(a, b0, acc[0][ct]);
                acc[1][ct] = mfma_bf16(a, b1v, acc[1][ct]);
            }
        }
        src = in1;
    }

#pragma unroll
    for (int st = 0; st < 2; ++st) {
        int node = n0 + rbase + st * 16 + c;
        if (node < N_NODES) {
#pragma unroll
            for (int ct = 0; ct < 8; ++ct) {
                int col = ct * 16 + quad * 4;
                float4 bv = make_float4(0.f, 0.f, 0.f, 0.f);
                if (HASB) bv = *(const float4*)(bias + col);
                float v0 = acc[st][ct][0] + bv.x;
                float v1 = acc[st][ct][1] + bv.y;
                float v2 = acc[st][ct][2] + bv.z;
                float v3 = acc[st][ct][3] + bv.w;
                if (SSP) { v0 = sspf(v0); v1 = sspf(v1); v2 = sspf(v2); v3 = sspf(v3); }
                if (RES) {
                    float4 rv = *(const float4*)(resid + (size_t)node * 128 + col);
                    v0 += rv.x; v1 += rv.y; v2 += rv.z; v3 += rv.w;
                }
                if (BF16OUT) {
                    uint2 p; p.x = pack2(v0, v1); p.y = pack2(v2, v3);
                    *(uint2*)((ushort_t*)outp + (size_t)node * 128 + col) = p;
                } else {
                    *(float4*)((float*)outp + (size_t)node * 128 + col) =
                        make_float4(v0, v1, v2, v3);
                }
            }
        }
    }
}

// ---------------------------------------------------------------------------
extern "C" void kernel_launch(void* const* d_in, const int* in_sizes, int n_in,
                              void* d_out, int out_size, void* d_ws, size_t ws_size,
                              hipStream_t stream) {
    const float* z        = (const float*)d_in[0];
    const int*   ei       = (const int*)d_in[1];
    const float* el       = (const float*)d_in[2];
    const float* ea       = (const float*)d_in[3];
    const float* emblin_w = (const float*)d_in[4];
    const float* emblin_b = (const float*)d_in[5];
    const float* mlp_w1   = (const float*)d_in[6];
    const float* mlp_b1   = (const float*)d_in[7];
    const float* mlp_w2   = (const float*)d_in[8];
    const float* mlp_b2   = (const float*)d_in[9];
    const float* lin1_w   = (const float*)d_in[10];
    const float* lin2_w   = (const float*)d_in[11];
    const float* lin2_b   = (const float*)d_in[12];
    const float* lin_w    = (const float*)d_in[13];
    const float* lin_b    = (const float*)d_in[14];
    (void)in_sizes; (void)n_in; (void)out_size; (void)ws_size;

    const size_t ND = (size_t)N_NODES * D;
    float* ws   = (float*)d_ws;
    float* h    = ws;                // N*D fp32
    float* m_i  = h + ND;            // N*D fp32
    float* c_mask = m_i + ND;        // E fp32
    float* fend = c_mask + E_EDGES;

    ushort_t* w1b     = (ushort_t*)fend;                     // L*D*128
    ushort_t* w2b     = w1b   + (size_t)L_LAYERS * D * 128;  // L*D*D
    ushort_t* lin1b   = w2b   + (size_t)L_LAYERS * D * D;    // L*D*D
    ushort_t* lin2b   = lin1b + (size_t)L_LAYERS * D * D;    // L*D*D
    ushort_t* linwb   = lin2b + (size_t)L_LAYERS * D * D;    // L*D*256
    ushort_t* xf_bf   = linwb + (size_t)L_LAYERS * D * 256;  // N*128
    ushort_t* attr_bf = xf_bf + ND;                          // E*128
    int* ibase      = (int*)(attr_bf + (size_t)E_EDGES * 128);
    int* deg        = ibase;                 // N
    int* row_start  = deg + N_NODES;         // N+1
    int* cursor     = row_start + N_NODES + 1;
    int* perm       = cursor + N_NODES;      // E
    int* src_p      = perm + E_EDGES;        // E
    int* dst_p      = src_p + E_EDGES;       // E

    // one-time weight prep
    convw1_kernel<<<(L_LAYERS * D * 128) / 256, 256, 0, stream>>>(mlp_w1, w1b);
    castbf_kernel<<<(L_LAYERS * D * D) / 256, 256, 0, stream>>>(mlp_w2, w2b);
    castbf_kernel<<<(L_LAYERS * D * D) / 256, 256, 0, stream>>>(lin1_w, lin1b);
    castbf_kernel<<<(L_LAYERS * D * D) / 256, 256, 0, stream>>>(lin2_w, lin2b);
    castbf_kernel<<<(L_LAYERS * D * 256) / 256, 256, 0, stream>>>(lin_w, linwb);

    // CSR build + edge-side one-time prep
    hipMemsetAsync(deg, 0, (size_t)N_NODES * sizeof(int), stream);
    hist_kernel<<<E_EDGES / 256, 256, 0, stream>>>(ei, deg);
    scan_kernel<<<1, 1024, 0, stream>>>(deg, row_start, cursor);
    scatter_perm_kernel<<<E_EDGES / 256, 256, 0, stream>>>(ei, cursor, perm, src_p, dst_p);
    attr_prep_kernel<<<E_EDGES / 8, 256, 0, stream>>>(ea, perm, attr_bf);
    cmask_kernel<<<E_EDGES / 256, 256, 0, stream>>>(el, perm, c_mask);

    embed_kernel<<<N_NODES, D, 0, stream>>>(z, emblin_w, emblin_b, h);

    const int NBLK = (N_NODES + 127) / 128;   // 157
    const int EBLK = N_NODES / 16;            // 1250 (16 nodes/block, 8/wave)
    for (int l = 0; l < L_LAYERS; ++l) {
        // xf_bf = h @ lin1^T (bf16 out)
        node_mfma_kernel<false, false, false, true, false><<<NBLK, 256, 0, stream>>>(
            h, nullptr, lin1b + (size_t)l * D * D, nullptr, nullptr, xf_bf);
        // fused edge MLP + owned segment sum -> m_i (no atomics, no memset)
        edge_fused_kernel<<<EBLK, 128, 0, stream>>>(
            attr_bf, c_mask, src_p, dst_p, row_start, xf_bf,
            w1b + (size_t)l * D * 128, mlp_b1 + (size_t)l * D,
            w2b + (size_t)l * D * D, mlp_b2 + (size_t)l * D, m_i);
        // m_i = ssp(m_i @ lin2^T + b) in place
        node_mfma_kernel<true, true, false, false, false><<<NBLK, 256, 0, stream>>>(
            m_i, nullptr, lin2b + (size_t)l * D * D, lin2_b + (size_t)l * D,
            nullptr, m_i);
        // h = h + concat(h, m_i) @ lin_w^T + b in place
        node_mfma_kernel<true, false, true, false, true><<<NBLK, 256, 0, stream>>>(
            h, m_i, linwb + (size_t)l * D * 256, lin_b + (size_t)l * D, h, h);
    }

    hipMemcpyAsync(d_out, h, ND * sizeof(float), hipMemcpyDeviceToDevice, stream);
}